// Round 13
// baseline (98.240 us; speedup 1.0000x reference)
//
#include <hip/hip_runtime.h>
#include <math.h>

#define NFEAT  512
#define NHID   128
#define NCLASS 70
#define NIDX   10000
#define NTILE  625
#define HELEMS (2u * NIDX * NHID)          // 2,560,000 ushorts: H scratch
#define GELEMS (2u * NIDX * NHID)          // 2,560,000 ushorts: G12 scratch
#define WIMG_ELEMS (2u * 128 * 512)        // 131,072 ushorts: W0/W1 LDS images
#define SMALL_ELEMS 74496u                 // G1,G2,GT,Wc row-major bf16
#define CNT_OFF ((size_t)(HELEMS + GELEMS + WIMG_ELEMS + SMALL_ELEMS) * 2)
#define WS_NEED (CNT_OFF + 512)

typedef float  f32x4  __attribute__((ext_vector_type(4)));
typedef __bf16 bf16x8 __attribute__((ext_vector_type(8)));

static __device__ __forceinline__ unsigned short f2bf(float f) {
    unsigned u = __builtin_bit_cast(unsigned, f);
    u += 0x7fffu + ((u >> 16) & 1u);
    return (unsigned short)(u >> 16);
}
static __device__ __forceinline__ float bf2f(unsigned short h) {
    unsigned u = ((unsigned)h) << 16;
    return __builtin_bit_cast(float, u);
}
static __device__ __forceinline__ bf16x8 pack8(float4 a, float4 b) {
    bf16x8 r;
    r[0] = (__bf16)a.x; r[1] = (__bf16)a.y; r[2] = (__bf16)a.z; r[3] = (__bf16)a.w;
    r[4] = (__bf16)b.x; r[5] = (__bf16)b.y; r[6] = (__bf16)b.z; r[7] = (__bf16)b.w;
    return r;
}
static __device__ __forceinline__ bf16x8 pack8s(float4 a, float4 b, float s) {
    bf16x8 r;
    r[0] = (__bf16)(a.x * s); r[1] = (__bf16)(a.y * s); r[2] = (__bf16)(a.z * s); r[3] = (__bf16)(a.w * s);
    r[4] = (__bf16)(b.x * s); r[5] = (__bf16)(b.y * s); r[6] = (__bf16)(b.z * s); r[7] = (__bf16)(b.w * s);
    return r;
}
static __device__ __forceinline__ f32x4 MFMA(bf16x8 a, bf16x8 b, f32x4 c) {
    return __builtin_amdgcn_mfma_f32_16x16x32_bf16(a, b, c, 0, 0, 0);
}
static __device__ __forceinline__ bf16x8 ldsAx(const unsigned short* base, int row, int colb, int rstride) {
    return *(const bf16x8*)((const char*)base + row * rstride + (colb ^ ((row & 7) << 4)));
}
static __device__ __forceinline__ void ldsW1(unsigned short* base, int row, int col, unsigned short v) {
    *(unsigned short*)((char*)base + row * 256 + ((col * 2) ^ ((row & 7) << 4))) = v;
}
static __device__ __forceinline__ float ldsR1(const unsigned short* base, int row, int col) {
    return bf2f(*(const unsigned short*)((const char*)base + row * 256 + ((col * 2) ^ ((row & 7) << 4))));
}

// ---- prep: W0/W1 -> pre-swizzled bf16 LDS images; G1/G2/GT/Wc -> row-major bf16 ----
__global__ void prep_weights(const float* __restrict__ W0, const float* __restrict__ W1,
                             const float* __restrict__ G1, const float* __restrict__ G2,
                             const float* __restrict__ GT, const float* __restrict__ Wc,
                             unsigned short* __restrict__ wsWimg,
                             unsigned short* __restrict__ wsSmall) {
    int i = blockIdx.x * 256 + threadIdx.x;
    if (i < 16384) {
        int t = i >> 13;
        int r = i & 8191;
        int n = r >> 6, k8 = r & 63;
        const float* src = (t ? W1 : W0) + (size_t)n * NFEAT + k8 * 8;
        float4 a = ((const float4*)src)[0], b = ((const float4*)src)[1];
        char* dst = (char*)wsWimg + t * 131072 + n * 1024 + ((k8 * 16) ^ ((n & 7) << 4));
        *(bf16x8*)dst = pack8(a, b);
    } else {
        int i4 = i - 16384;
        if (i4 >= 18624) return;
        const float* src; int base4, dstb;
        if      (i4 < 4096)  { src = G1; base4 = 0;     dstb = 0; }
        else if (i4 < 8192)  { src = G2; base4 = 4096;  dstb = 16384; }
        else if (i4 < 16384) { src = GT; base4 = 8192;  dstb = 32768; }
        else                 { src = Wc; base4 = 16384; dstb = 65536; }
        float4 v = ((const float4*)src)[i4 - base4];
        ushort4 o;
        o.x = f2bf(v.x); o.y = f2bf(v.y); o.z = f2bf(v.z); o.w = f2bf(v.w);
        *(ushort4*)(wsSmall + dstb + (size_t)(i4 - base4) * 4) = o;
    }
}

// ---- fused producer-consumer kernel: stage B+C (all blocks) + tail D/E/softmax
// (second-arriving block per tile-group, via device-scope atomic handoff) ----
__global__ __launch_bounds__(512) void hyperFused(
    const float* __restrict__ x, const float* __restrict__ sf,
    const int* __restrict__ idx,
    const unsigned short* __restrict__ wsWimg,
    const unsigned short* __restrict__ wsSmall,
    unsigned short* __restrict__ wsH,
    unsigned short* __restrict__ wsG,
    int* __restrict__ cnt,
    float* __restrict__ out)
{
    __shared__ __align__(16) char SM[155648];   // phase1: Wl|Xl|Hl|Gl ; phase2: Hb|Gb|FX
    __shared__ float scl2s[5][16];
    __shared__ int wflag;

    unsigned short* Wl = (unsigned short*)SM;              // 128 KB
    unsigned short* Xl = (unsigned short*)(SM + 131072);   // 16 KB
    unsigned short* Hl = (unsigned short*)(SM + 147456);   // 4 KB
    unsigned short* Gl = (unsigned short*)(SM + 151552);   // 4 KB

    const int tid  = threadIdx.x;
    const int w    = tid >> 6;
    const int lane = tid & 63;
    const int ln   = lane & 15, lg = lane >> 4;
    const int bid  = blockIdx.x;
    const int t    = bid / 125, tb = bid % 125;
    const int tile0 = tb * 5;
    const float* XS = t ? sf : x;
    const f32x4 zero4 = {0.f, 0.f, 0.f, 0.f};

    // gather volley for tile 0 — longest latency, issue first
    float4 ga0, ga1, gb0, gb1;
    {
        int r0 = idx[tile0 * 16 + w];
        int r1 = idx[tile0 * 16 + w + 8];
        const float4* p0 = (const float4*)(XS + (size_t)r0 * NFEAT + lane * 8);
        const float4* p1 = (const float4*)(XS + (size_t)r1 * NFEAT + lane * 8);
        ga0 = p0[0]; ga1 = p0[1];
        gb0 = p1[0]; gb1 = p1[1];
    }
    // stage-C fragments for this tensor (amortized over 5 tiles)
    bf16x8 cf[4];
    {
        const unsigned short* Gsm = wsSmall + t * 16384;   // G1 or G2 bf16
        #pragma unroll
        for (int kc = 0; kc < 4; ++kc)
            cf[kc] = *(const bf16x8*)(Gsm + (size_t)(w * 16 + ln) * NHID + kc * 32 + lg * 8);
    }
    // W image -> LDS (L2-hot after first blocks)
    {
        const uint4* src = (const uint4*)((const char*)wsWimg + (size_t)t * 131072);
        uint4* dst = (uint4*)Wl;
        #pragma unroll
        for (int i = 0; i < 16; ++i) dst[tid + i * 512] = src[tid + i * 512];
    }
    auto putX = [&](int m, float4 a, float4 b) {
        float ss = a.x*a.x + a.y*a.y + a.z*a.z + a.w*a.w
                 + b.x*b.x + b.y*b.y + b.z*b.z + b.w*b.w;
        #pragma unroll
        for (int d = 1; d < 64; d <<= 1) ss += __shfl_xor(ss, d);
        float scl = (ss > 0.f) ? (1.f / sqrtf(ss)) : 0.f;
        *(bf16x8*)((char*)Xl + m * 1024 + ((lane * 16) ^ ((m & 7) << 4))) = pack8s(a, b, scl);
    };
    putX(w,     ga0, ga1);
    putX(w + 8, gb0, gb1);
    __syncthreads();

    for (int it = 0; it < 5; ++it) {
        float4 na0, na1, nb0, nb1;
        if (it < 4) {
            int tile = tile0 + it + 1;
            int r0 = idx[tile * 16 + w];
            int r1 = idx[tile * 16 + w + 8];
            const float4* p0 = (const float4*)(XS + (size_t)r0 * NFEAT + lane * 8);
            const float4* p1 = (const float4*)(XS + (size_t)r1 * NFEAT + lane * 8);
            na0 = p0[0]; na1 = p0[1];
            nb0 = p1[0]; nb1 = p1[1];
        }
        // stage B
        f32x4 accE = zero4, accO = zero4;
        #pragma unroll
        for (int kc = 0; kc < 16; ++kc) {
            bf16x8 a = ldsAx(Xl, ln,          kc * 64 + lg * 16, 1024);
            bf16x8 b = ldsAx(Wl, w * 16 + ln, kc * 64 + lg * 16, 1024);
            if (kc & 1) accO = MFMA(a, b, accO); else accE = MFMA(a, b, accE);
        }
        f32x4 acc = accE + accO;
        #pragma unroll
        for (int rg = 0; rg < 4; ++rg)
            ldsW1(Hl, lg * 4 + rg, w * 16 + ln, f2bf(fmaxf(acc[rg], 0.f)));
        __syncthreads();   // Hl ready

        // stage C
        f32x4 aC = zero4;
        #pragma unroll
        for (int kc = 0; kc < 4; ++kc) {
            bf16x8 a = ldsAx(Hl, ln, kc * 64 + lg * 16, 256);
            aC = MFMA(a, cf[kc], aC);
        }
        if (tid < 256) {
            int tile = tile0 + it;
            ((uint4*)(wsH + ((size_t)t * NIDX + (size_t)tile * 16) * NHID))[tid]
                = ((const uint4*)Hl)[tid];
        }
        if (it < 4) {
            putX(w,     na0, na1);
            putX(w + 8, nb0, nb1);
        }
        #pragma unroll
        for (int rg = 0; rg < 4; ++rg)
            ldsW1(Gl, lg * 4 + rg, w * 16 + ln, f2bf(aC[rg]));
        __syncthreads();   // Gl ready; Xl ready for next iter

        if (tid < 256) {
            int tile = tile0 + it;
            ((uint4*)(wsG + ((size_t)t * NIDX + (size_t)tile * 16) * NHID))[tid]
                = ((const uint4*)Gl)[tid];
        }
    }

    // --- tail-phase weight volleys (issued pre-atomic; latency hides under fence) ---
    const int nD = w * 16 + ln;
    const unsigned short* GTp = wsSmall + 32768;
    const unsigned short* Wcp = wsSmall + 65536;
    bf16x8 gt[8];
    #pragma unroll
    for (int kc = 0; kc < 8; ++kc)
        gt[kc] = *(const bf16x8*)(GTp + (size_t)nD * (2 * NHID) + kc * 32 + lg * 8);
    const int ccE = nD;
    const int ccl = (ccE < NCLASS) ? ccE : 0;
    bf16x8 wcf[4];
    #pragma unroll
    for (int kc = 0; kc < 4; ++kc)
        wcf[kc] = *(const bf16x8*)(Wcp + (size_t)ccl * NHID + kc * 32 + lg * 8);

    // --- release + handoff: second arriver per tile-group runs the tail ---
    __threadfence();     // all threads: order H/G stores device-wide
    __syncthreads();
    if (tid == 0) wflag = atomicAdd(&cnt[tb], 1);
    __syncthreads();
    if (wflag != 1) return;
    __threadfence();     // acquire: see partner block's H/G

    // ================= tail: stages D/E + softmax for 5 tiles =================
    unsigned short* Hb = (unsigned short*)SM;              // [5][2][16][128] 40 KB
    unsigned short* Gb = (unsigned short*)(SM + 40960);    // [5][2][16][128] 40 KB
    unsigned short* FX = (unsigned short*)(SM + 81920);    // [5][16][128]    20 KB
    float* LOGb = (float*)SM;                              // [5][16][80] aliases Hb after D

    #pragma unroll
    for (int i = 0; i < 5; ++i) {
        int q = tid + i * 512;             // 0..2559 over [ti][tt][256 uint4]
        int seg = q >> 8, r = q & 255;
        int ti = seg >> 1, tt = seg & 1;
        size_t off = ((size_t)tt * NIDX + (size_t)(tile0 + ti) * 16) * NHID;
        ((uint4*)Hb)[q] = ((const uint4*)(wsH + off))[r];
        ((uint4*)Gb)[q] = ((const uint4*)(wsG + off))[r];
    }
    __syncthreads();   // t1

    // stage D: all 5 tiles
    #pragma unroll
    for (int ti = 0; ti < 5; ++ti) {
        f32x4 aE = zero4, aO = zero4;
        #pragma unroll
        for (int kc = 0; kc < 8; ++kc) {
            const unsigned short* As = Gb + ti * 4096 + (kc >> 2) * 2048;
            bf16x8 a = ldsAx(As, ln, (kc & 3) * 64 + lg * 16, 256);
            if (kc & 1) aO = MFMA(a, gt[kc], aO); else aE = MFMA(a, gt[kc], aE);
        }
        f32x4 accD = aE + aO;
        #pragma unroll
        for (int rg = 0; rg < 4; ++rg) {
            int m = lg * 4 + rg;
            float g  = 1.f / (1.f + __expf(-accD[rg]));
            float h0 = ldsR1(Hb + ti * 4096,        m, nD);
            float h1 = ldsR1(Hb + ti * 4096 + 2048, m, nD);
            ldsW1(FX + ti * 2048, m, nD, f2bf((1.f - g) * h0 + g * h1));
        }
    }
    __syncthreads();   // t2

    // fix norms: 80 rows over 32 row-slots x 16 lanes
    {
        int rr = tid >> 4, sl = tid & 15;
        #pragma unroll
        for (int j = 0; j < 3; ++j) {
            int rs = j * 32 + rr;
            if (rs < 80) {
                int ti = rs >> 4, r = rs & 15;
                bf16x8 v = ldsAx(FX + ti * 2048, r, sl * 16, 256);
                float ss = 0.f;
                #pragma unroll
                for (int jj = 0; jj < 8; ++jj) { float f = (float)v[jj]; ss += f * f; }
                ss += __shfl_xor(ss, 1); ss += __shfl_xor(ss, 2);
                ss += __shfl_xor(ss, 4); ss += __shfl_xor(ss, 8);
                if (sl == 0) scl2s[ti][r] = (ss > 0.f) ? (1.f / sqrtf(ss)) : 0.f;
            }
        }
    }
    __syncthreads();   // t3

    // stage E: all 5 tiles (waves 0..4); LOG aliases Hb (dead after D)
    if (w < 5) {
        const bool live = (ccE < NCLASS);
        bf16x8 bfz;
        #pragma unroll
        for (int j = 0; j < 8; ++j) bfz[j] = (__bf16)0.f;
        #pragma unroll
        for (int ti = 0; ti < 5; ++ti) {
            f32x4 accE = zero4;
            #pragma unroll
            for (int kc = 0; kc < 4; ++kc) {
                bf16x8 a = ldsAx(FX + ti * 2048, ln, kc * 64 + lg * 16, 256);
                accE = MFMA(a, live ? wcf[kc] : bfz, accE);
            }
            if (live) {
                float* LO = LOGb + ti * 1280;
                #pragma unroll
                for (int rg = 0; rg < 4; ++rg) {
                    int m = lg * 4 + rg;
                    LO[m * 80 + ccE] = fmaxf(accE[rg] * scl2s[ti][m], 0.f);
                }
            }
        }
    }
    __syncthreads();   // t4

    // log_softmax + store: 80 rows over 32 row-slots x 16 lanes, 5 classes/lane
    {
        int rr = tid >> 4, l16 = tid & 15;
        #pragma unroll
        for (int j = 0; j < 3; ++j) {
            int rs = j * 32 + rr;
            if (rs < 80) {
                int ti = rs >> 4, r = rs & 15;
                const float* LO = LOGb + ti * 1280 + r * 80;
                float v[5];
                #pragma unroll
                for (int jj = 0; jj < 5; ++jj) {
                    int c = l16 + jj * 16;
                    v[jj] = (c < NCLASS) ? LO[c] : -1e30f;
                }
                float mx = v[0];
                #pragma unroll
                for (int jj = 1; jj < 5; ++jj) mx = fmaxf(mx, v[jj]);
                mx = fmaxf(mx, __shfl_xor(mx, 1)); mx = fmaxf(mx, __shfl_xor(mx, 2));
                mx = fmaxf(mx, __shfl_xor(mx, 4)); mx = fmaxf(mx, __shfl_xor(mx, 8));
                float se = 0.f;
                #pragma unroll
                for (int jj = 0; jj < 5; ++jj) {
                    int c = l16 + jj * 16;
                    if (c < NCLASS) se += __expf(v[jj] - mx);
                }
                se += __shfl_xor(se, 1); se += __shfl_xor(se, 2);
                se += __shfl_xor(se, 4); se += __shfl_xor(se, 8);
                float lz = mx + __logf(se);
                size_t orow = (size_t)(tile0 + ti) * 16 + r;
                #pragma unroll
                for (int jj = 0; jj < 5; ++jj) {
                    int c = l16 + jj * 16;
                    if (c < NCLASS) out[orow * NCLASS + c] = v[jj] - lz;
                }
            }
        }
    }
}

// ---- fallback (ws too small): fused kernel, f32 weights inline ----
static __device__ __forceinline__ bf16x8 bfragF(const float* p, size_t off) {
    const float4* q = (const float4*)(p + off);
    return pack8(q[0], q[1]);
}
__global__ __launch_bounds__(512) void hyper_fb(
    const float* __restrict__ x, const float* __restrict__ sf,
    const int* __restrict__ idx,
    const float* __restrict__ W0, const float* __restrict__ W1,
    const float* __restrict__ G1, const float* __restrict__ G2,
    const float* __restrict__ GT, const float* __restrict__ Wc,
    float* __restrict__ out)
{
    __shared__ __align__(16) unsigned short Xbuf[2][16][NFEAT];
    __shared__ __align__(16) unsigned short Hbuf[2][16][NHID];
    __shared__ float scl2[16];
    unsigned short* G12 = &Xbuf[0][0][0];
    unsigned short* FIX = &Xbuf[0][0][0] + 4096;
    float*          LOG = (float*)(&Xbuf[0][0][0] + 6144);

    const int tid = threadIdx.x, bid = blockIdx.x;
    const int w = tid >> 6, lane = tid & 63;
    const int ln = lane & 15, lg = lane >> 4;
    const int tB = w >> 2, nq = w & 3;
    const f32x4 zero4 = {0.f, 0.f, 0.f, 0.f};

    {
        char* xb = (char*)&Xbuf[0][0][0];
        #pragma unroll
        for (int j = 0; j < 4; ++j) {
            int p = w * 4 + j, t = p >> 4, m = p & 15;
            int ri = idx[bid * 16 + m];
            const float4* q = (const float4*)((t ? sf : x) + (size_t)ri * NFEAT + lane * 8);
            float4 a = q[0], b = q[1];
            float ss = a.x*a.x + a.y*a.y + a.z*a.z + a.w*a.w
                     + b.x*b.x + b.y*b.y + b.z*b.z + b.w*b.w;
            #pragma unroll
            for (int d = 1; d < 64; d <<= 1) ss += __shfl_xor(ss, d);
            float scl = (ss > 0.f) ? (1.f / sqrtf(ss)) : 0.f;
            int soff = t * 16384 + m * 1024 + ((lane * 16) ^ ((m & 7) << 4));
            *(bf16x8*)(xb + soff) = pack8s(a, b, scl);
        }
    }
    __syncthreads();
    {
        const float* Wp = tB ? W1 : W0;
        f32x4 acc0 = zero4, acc1 = zero4;
        const unsigned short* Xb = (const unsigned short*)((const char*)&Xbuf[0][0][0] + tB * 16384);
        #pragma unroll
        for (int kc = 0; kc < 16; ++kc) {
            bf16x8 a = ldsAx(Xb, ln, kc * 64 + lg * 16, 1024);
            acc0 = MFMA(a, bfragF(Wp, (size_t)(nq * 32 + ln) * NFEAT + kc * 32 + lg * 8), acc0);
            acc1 = MFMA(a, bfragF(Wp, (size_t)(nq * 32 + 16 + ln) * NFEAT + kc * 32 + lg * 8), acc1);
        }
        unsigned short* Hb = &Hbuf[tB][0][0];
        #pragma unroll
        for (int rg = 0; rg < 4; ++rg) {
            int m = lg * 4 + rg;
            ldsW1(Hb, m, nq * 32 + ln,      f2bf(fmaxf(acc0[rg], 0.f)));
            ldsW1(Hb, m, nq * 32 + 16 + ln, f2bf(fmaxf(acc1[rg], 0.f)));
        }
    }
    __syncthreads();
    {
        const float* Gp = tB ? G2 : G1;
        const unsigned short* Hs = &Hbuf[tB][0][0];
        f32x4 accC[2] = {zero4, zero4};
        #pragma unroll
        for (int kc = 0; kc < 4; ++kc) {
            bf16x8 a = ldsAx(Hs, ln, kc * 64 + lg * 16, 256);
            accC[0] = MFMA(a, bfragF(Gp, (size_t)(nq * 32 + ln) * NHID + kc * 32 + lg * 8), accC[0]);
            accC[1] = MFMA(a, bfragF(Gp, (size_t)(nq * 32 + 16 + ln) * NHID + kc * 32 + lg * 8), accC[1]);
        }
        unsigned short* Gd = G12 + tB * 2048;
        #pragma unroll
        for (int nt = 0; nt < 2; ++nt)
            #pragma unroll
            for (int rg = 0; rg < 4; ++rg) {
                int m = lg * 4 + rg;
                ldsW1(Gd, m, nq * 32 + nt * 16 + ln, f2bf(accC[nt][rg]));
            }
    }
    __syncthreads();
    {
        f32x4 accD = zero4;
        const int n = w * 16 + ln;
        #pragma unroll
        for (int kc = 0; kc < 8; ++kc) {
            const unsigned short* As = G12 + (kc >> 2) * 2048;
            bf16x8 a = ldsAx(As, ln, (kc & 3) * 64 + lg * 16, 256);
            accD = MFMA(a, bfragF(GT, (size_t)n * (2 * NHID) + kc * 32 + lg * 8), accD);
        }
        #pragma unroll
        for (int rg = 0; rg < 4; ++rg) {
            int m = lg * 4 + rg;
            float g  = 1.f / (1.f + __expf(-accD[rg]));
            float h0 = ldsR1(&Hbuf[0][0][0], m, n);
            float h1 = ldsR1(&Hbuf[1][0][0], m, n);
            ldsW1(FIX, m, n, f2bf((1.f - g) * h0 + g * h1));
        }
    }
    __syncthreads();
    if (tid < 256) {
        int r = tid >> 4, sl = tid & 15;
        bf16x8 v = ldsAx(FIX, r, sl * 16, 256);
        float ss = 0.f;
        #pragma unroll
        for (int j = 0; j < 8; ++j) { float f = (float)v[j]; ss += f * f; }
        ss += __shfl_xor(ss, 1); ss += __shfl_xor(ss, 2);
        ss += __shfl_xor(ss, 4); ss += __shfl_xor(ss, 8);
        if (sl == 0) scl2[r] = (ss > 0.f) ? (1.f / sqrtf(ss)) : 0.f;
    }
    __syncthreads();
    if (w < 5) {
        const int cc = w * 16 + ln;
        bf16x8 bfz;
        #pragma unroll
        for (int j = 0; j < 8; ++j) bfz[j] = (__bf16)0.f;
        f32x4 accE = zero4;
        #pragma unroll
        for (int kc = 0; kc < 4; ++kc) {
            bf16x8 a = ldsAx(FIX, ln, kc * 64 + lg * 16, 256);
            bf16x8 b = (cc < NCLASS) ? bfragF(Wc, (size_t)cc * NHID + kc * 32 + lg * 8) : bfz;
            accE = MFMA(a, b, accE);
        }
        #pragma unroll
        for (int rg = 0; rg < 4; ++rg) {
            int m = lg * 4 + rg;
            float v = fmaxf(accE[rg] * scl2[m], 0.f);
            LOG[m * 80 + cc] = (cc < NCLASS) ? v : -1e30f;
        }
    }
    __syncthreads();
    {
        const int r = tid >> 5, l32 = tid & 31;
        float v0 = LOG[r * 80 + l32];
        float v1 = LOG[r * 80 + 32 + l32];
        float v2 = (l32 < 16) ? LOG[r * 80 + 64 + l32] : -1e30f;
        float mx = fmaxf(fmaxf(v0, v1), v2);
        #pragma unroll
        for (int d = 1; d < 32; d <<= 1) mx = fmaxf(mx, __shfl_xor(mx, d, 32));
        float se = __expf(v0 - mx) + __expf(v1 - mx) + ((l32 < 16) ? __expf(v2 - mx) : 0.f);
        #pragma unroll
        for (int d = 1; d < 32; d <<= 1) se += __shfl_xor(se, d, 32);
        float lz = mx + __logf(se);
        size_t orow = (size_t)bid * 16 + r;
        out[orow * NCLASS + l32] = v0 - lz;
        if (l32 + 32 < NCLASS) out[orow * NCLASS + 32 + l32] = v1 - lz;
        if (l32 + 64 < NCLASS) out[orow * NCLASS + 64 + l32] = v2 - lz;
    }
}

extern "C" void kernel_launch(void* const* d_in, const int* in_sizes, int n_in,
                              void* d_out, int out_size, void* d_ws, size_t ws_size,
                              hipStream_t stream)
{
    const float* x   = (const float*)d_in[0];
    const float* sf  = (const float*)d_in[1];
    const int*   idx = (const int*)d_in[2];
    const float* W0  = (const float*)d_in[3];
    const float* W1  = (const float*)d_in[4];
    const float* G1  = (const float*)d_in[5];
    const float* G2  = (const float*)d_in[6];
    const float* GT  = (const float*)d_in[7];
    const float* Wc  = (const float*)d_in[8];
    float* out = (float*)d_out;

    if (ws_size >= WS_NEED) {
        unsigned short* wsH     = (unsigned short*)d_ws;
        unsigned short* wsG     = wsH + HELEMS;
        unsigned short* wsWimg  = wsG + GELEMS;
        unsigned short* wsSmall = wsWimg + WIMG_ELEMS;
        int* cnt = (int*)((char*)d_ws + CNT_OFF);
        hipMemsetAsync(cnt, 0, 128 * sizeof(int), stream);   // graph-safe, per-replay reset
        prep_weights<<<dim3(137), dim3(256), 0, stream>>>(W0, W1, G1, G2, GT, Wc, wsWimg, wsSmall);
        hyperFused<<<dim3(250), dim3(512), 0, stream>>>(
            x, sf, idx, wsWimg, wsSmall, wsH, wsG, cnt, out);
    } else {
        hyper_fb<<<dim3(NTILE), dim3(512), 0, stream>>>(
            x, sf, idx, W0, W1, G1, G2, GT, Wc, out);
    }
}

// Round 14
// 37.023 us; speedup vs baseline: 2.6535x; 2.6535x over previous
//
#include <hip/hip_runtime.h>
#include <math.h>

#define NFEAT  512
#define NHID   128
#define NCLASS 70
#define NIDX   10000
#define NTILE  625
#define HELEMS (2u * NIDX * NHID)          // 2,560,000 ushorts: H scratch
#define GELEMS (2u * NIDX * NHID)          // 2,560,000 ushorts: G12 scratch
#define WIMG_ELEMS (2u * 128 * 512)        // 131,072 ushorts: W0/W1 LDS images
#define SMALL_ELEMS 74496u                 // G1,G2,GT,Wc row-major bf16
#define WS_NEED ((size_t)(HELEMS + GELEMS + WIMG_ELEMS + SMALL_ELEMS) * 2)

typedef float  f32x4  __attribute__((ext_vector_type(4)));
typedef __bf16 bf16x8 __attribute__((ext_vector_type(8)));

static __device__ __forceinline__ unsigned short f2bf(float f) {
    unsigned u = __builtin_bit_cast(unsigned, f);
    u += 0x7fffu + ((u >> 16) & 1u);
    return (unsigned short)(u >> 16);
}
static __device__ __forceinline__ float bf2f(unsigned short h) {
    unsigned u = ((unsigned)h) << 16;
    return __builtin_bit_cast(float, u);
}
static __device__ __forceinline__ bf16x8 pack8(float4 a, float4 b) {
    bf16x8 r;
    r[0] = (__bf16)a.x; r[1] = (__bf16)a.y; r[2] = (__bf16)a.z; r[3] = (__bf16)a.w;
    r[4] = (__bf16)b.x; r[5] = (__bf16)b.y; r[6] = (__bf16)b.z; r[7] = (__bf16)b.w;
    return r;
}
static __device__ __forceinline__ bf16x8 pack8s(float4 a, float4 b, float s) {
    bf16x8 r;
    r[0] = (__bf16)(a.x * s); r[1] = (__bf16)(a.y * s); r[2] = (__bf16)(a.z * s); r[3] = (__bf16)(a.w * s);
    r[4] = (__bf16)(b.x * s); r[5] = (__bf16)(b.y * s); r[6] = (__bf16)(b.z * s); r[7] = (__bf16)(b.w * s);
    return r;
}
static __device__ __forceinline__ f32x4 MFMA(bf16x8 a, bf16x8 b, f32x4 c) {
    return __builtin_amdgcn_mfma_f32_16x16x32_bf16(a, b, c, 0, 0, 0);
}
static __device__ __forceinline__ bf16x8 ldsAx(const unsigned short* base, int row, int colb, int rstride) {
    return *(const bf16x8*)((const char*)base + row * rstride + (colb ^ ((row & 7) << 4)));
}
static __device__ __forceinline__ void ldsW1(unsigned short* base, int row, int col, unsigned short v) {
    *(unsigned short*)((char*)base + row * 256 + ((col * 2) ^ ((row & 7) << 4))) = v;
}
static __device__ __forceinline__ float ldsR1(const unsigned short* base, int row, int col) {
    return bf2f(*(const unsigned short*)((const char*)base + row * 256 + ((col * 2) ^ ((row & 7) << 4))));
}

// ---- prep: W0/W1 -> pre-swizzled bf16 LDS images; G1/G2/GT/Wc -> row-major bf16 ----
__global__ void prep_weights(const float* __restrict__ W0, const float* __restrict__ W1,
                             const float* __restrict__ G1, const float* __restrict__ G2,
                             const float* __restrict__ GT, const float* __restrict__ Wc,
                             unsigned short* __restrict__ wsWimg,
                             unsigned short* __restrict__ wsSmall) {
    int i = blockIdx.x * 256 + threadIdx.x;
    if (i < 16384) {
        int t = i >> 13;
        int r = i & 8191;
        int n = r >> 6, k8 = r & 63;
        const float* src = (t ? W1 : W0) + (size_t)n * NFEAT + k8 * 8;
        float4 a = ((const float4*)src)[0], b = ((const float4*)src)[1];
        char* dst = (char*)wsWimg + t * 131072 + n * 1024 + ((k8 * 16) ^ ((n & 7) << 4));
        *(bf16x8*)dst = pack8(a, b);
    } else {
        int i4 = i - 16384;
        if (i4 >= 18624) return;
        const float* src; int base4, dstb;
        if      (i4 < 4096)  { src = G1; base4 = 0;     dstb = 0; }
        else if (i4 < 8192)  { src = G2; base4 = 4096;  dstb = 16384; }
        else if (i4 < 16384) { src = GT; base4 = 8192;  dstb = 32768; }
        else                 { src = Wc; base4 = 16384; dstb = 65536; }
        float4 v = ((const float4*)src)[i4 - base4];
        ushort4 o;
        o.x = f2bf(v.x); o.y = f2bf(v.y); o.z = f2bf(v.z); o.w = f2bf(v.w);
        *(ushort4*)(wsSmall + dstb + (size_t)(i4 - base4) * 4) = o;
    }
}

// ---- stage B+C, weights-stationary (r12, proven): 250 blocks, 5 tiles each ----
__global__ __launch_bounds__(512) void stageBC(
    const float* __restrict__ x, const float* __restrict__ sf,
    const int* __restrict__ idx,
    const unsigned short* __restrict__ wsWimg,
    const unsigned short* __restrict__ wsSmall,
    unsigned short* __restrict__ wsH,
    unsigned short* __restrict__ wsG)
{
    __shared__ __align__(16) unsigned short Wl[65536];  // 128 KB swizzled W image
    __shared__ __align__(16) unsigned short Xl[8192];   // 16 KB swizzled X tile
    __shared__ __align__(16) unsigned short Hl[2048];   // 4 KB swizzled H tile
    __shared__ __align__(16) unsigned short Gl[2048];   // 4 KB swizzled G12 tile

    const int tid  = threadIdx.x;
    const int w    = tid >> 6;
    const int lane = tid & 63;
    const int ln   = lane & 15, lg = lane >> 4;
    const int bid  = blockIdx.x;
    const int t    = bid / 125, tb = bid % 125;
    const int tile0 = tb * 5;
    const float* XS = t ? sf : x;
    const f32x4 zero4 = {0.f, 0.f, 0.f, 0.f};

    float4 ga0, ga1, gb0, gb1;
    {
        int r0 = idx[tile0 * 16 + w];
        int r1 = idx[tile0 * 16 + w + 8];
        const float4* p0 = (const float4*)(XS + (size_t)r0 * NFEAT + lane * 8);
        const float4* p1 = (const float4*)(XS + (size_t)r1 * NFEAT + lane * 8);
        ga0 = p0[0]; ga1 = p0[1];
        gb0 = p1[0]; gb1 = p1[1];
    }
    bf16x8 cf[4];
    {
        const unsigned short* Gsm = wsSmall + t * 16384;   // G1 or G2 bf16
        #pragma unroll
        for (int kc = 0; kc < 4; ++kc)
            cf[kc] = *(const bf16x8*)(Gsm + (size_t)(w * 16 + ln) * NHID + kc * 32 + lg * 8);
    }
    {
        const uint4* src = (const uint4*)((const char*)wsWimg + (size_t)t * 131072);
        uint4* dst = (uint4*)Wl;
        #pragma unroll
        for (int i = 0; i < 16; ++i) dst[tid + i * 512] = src[tid + i * 512];
    }
    auto putX = [&](int m, float4 a, float4 b) {
        float ss = a.x*a.x + a.y*a.y + a.z*a.z + a.w*a.w
                 + b.x*b.x + b.y*b.y + b.z*b.z + b.w*b.w;
        #pragma unroll
        for (int d = 1; d < 64; d <<= 1) ss += __shfl_xor(ss, d);
        float scl = (ss > 0.f) ? (1.f / sqrtf(ss)) : 0.f;
        *(bf16x8*)((char*)Xl + m * 1024 + ((lane * 16) ^ ((m & 7) << 4))) = pack8s(a, b, scl);
    };
    putX(w,     ga0, ga1);
    putX(w + 8, gb0, gb1);
    __syncthreads();

    for (int it = 0; it < 5; ++it) {
        float4 na0, na1, nb0, nb1;
        if (it < 4) {
            int tile = tile0 + it + 1;
            int r0 = idx[tile * 16 + w];
            int r1 = idx[tile * 16 + w + 8];
            const float4* p0 = (const float4*)(XS + (size_t)r0 * NFEAT + lane * 8);
            const float4* p1 = (const float4*)(XS + (size_t)r1 * NFEAT + lane * 8);
            na0 = p0[0]; na1 = p0[1];
            nb0 = p1[0]; nb1 = p1[1];
        }
        // stage B
        f32x4 accE = zero4, accO = zero4;
        #pragma unroll
        for (int kc = 0; kc < 16; ++kc) {
            bf16x8 a = ldsAx(Xl, ln,          kc * 64 + lg * 16, 1024);
            bf16x8 b = ldsAx(Wl, w * 16 + ln, kc * 64 + lg * 16, 1024);
            if (kc & 1) accO = MFMA(a, b, accO); else accE = MFMA(a, b, accE);
        }
        f32x4 acc = accE + accO;
        #pragma unroll
        for (int rg = 0; rg < 4; ++rg)
            ldsW1(Hl, lg * 4 + rg, w * 16 + ln, f2bf(fmaxf(acc[rg], 0.f)));
        __syncthreads();   // Hl ready

        // stage C
        f32x4 aC = zero4;
        #pragma unroll
        for (int kc = 0; kc < 4; ++kc) {
            bf16x8 a = ldsAx(Hl, ln, kc * 64 + lg * 16, 256);
            aC = MFMA(a, cf[kc], aC);
        }
        if (tid < 256) {
            int tile = tile0 + it;
            ((uint4*)(wsH + ((size_t)t * NIDX + (size_t)tile * 16) * NHID))[tid]
                = ((const uint4*)Hl)[tid];
        }
        if (it < 4) {
            putX(w,     na0, na1);
            putX(w + 8, nb0, nb1);
        }
        #pragma unroll
        for (int rg = 0; rg < 4; ++rg)
            ldsW1(Gl, lg * 4 + rg, w * 16 + ln, f2bf(aC[rg]));
        __syncthreads();   // Gl ready; Xl ready for next iter

        if (tid < 256) {
            int tile = tile0 + it;
            ((uint4*)(wsG + ((size_t)t * NIDX + (size_t)tile * 16) * NHID))[tid]
                = ((const uint4*)Gl)[tid];
        }
    }
}

// ---- tail: 125 blocks x 5 tiles; stages D/E + softmax (r13 phase-2 code, verified) ----
__global__ __launch_bounds__(512) void tailDE5(
    const unsigned short* __restrict__ wsSmall,
    const unsigned short* __restrict__ wsH,
    const unsigned short* __restrict__ wsG,
    float* __restrict__ out)
{
    __shared__ __align__(16) char SM[102400];  // Hb 40K | Gb 40K | FX 20K ; LOG aliases Hb
    __shared__ float scl2s[5][16];

    unsigned short* Hb = (unsigned short*)SM;              // [5][2][16][128]
    unsigned short* Gb = (unsigned short*)(SM + 40960);    // [5][2][16][128]
    unsigned short* FX = (unsigned short*)(SM + 81920);    // [5][16][128]
    float* LOGb = (float*)SM;                              // [5][16][80] aliases Hb after D

    const unsigned short* GTp = wsSmall + 32768;
    const unsigned short* Wcp = wsSmall + 65536;

    const int tid  = threadIdx.x;
    const int w    = tid >> 6;
    const int lane = tid & 63;
    const int ln   = lane & 15, lg = lane >> 4;
    const int tile0 = blockIdx.x * 5;
    const f32x4 zero4 = {0.f, 0.f, 0.f, 0.f};

    // entry volleys: H + G (80 KB, L2-resident) and weight fragments
    #pragma unroll
    for (int i = 0; i < 5; ++i) {
        int q = tid + i * 512;             // 0..2559 over [ti][tt][256 uint4]
        int seg = q >> 8, r = q & 255;
        int ti = seg >> 1, tt = seg & 1;
        size_t off = ((size_t)tt * NIDX + (size_t)(tile0 + ti) * 16) * NHID;
        ((uint4*)Hb)[q] = ((const uint4*)(wsH + off))[r];
        ((uint4*)Gb)[q] = ((const uint4*)(wsG + off))[r];
    }
    const int nD = w * 16 + ln;
    bf16x8 gt[8];
    #pragma unroll
    for (int kc = 0; kc < 8; ++kc)
        gt[kc] = *(const bf16x8*)(GTp + (size_t)nD * (2 * NHID) + kc * 32 + lg * 8);
    const int ccE = nD;
    const int ccl = (ccE < NCLASS) ? ccE : 0;
    bf16x8 wcf[4];
    #pragma unroll
    for (int kc = 0; kc < 4; ++kc)
        wcf[kc] = *(const bf16x8*)(Wcp + (size_t)ccl * NHID + kc * 32 + lg * 8);
    __syncthreads();   // t1

    // stage D: all 5 tiles
    #pragma unroll
    for (int ti = 0; ti < 5; ++ti) {
        f32x4 aE = zero4, aO = zero4;
        #pragma unroll
        for (int kc = 0; kc < 8; ++kc) {
            const unsigned short* As = Gb + ti * 4096 + (kc >> 2) * 2048;
            bf16x8 a = ldsAx(As, ln, (kc & 3) * 64 + lg * 16, 256);
            if (kc & 1) aO = MFMA(a, gt[kc], aO); else aE = MFMA(a, gt[kc], aE);
        }
        f32x4 accD = aE + aO;
        #pragma unroll
        for (int rg = 0; rg < 4; ++rg) {
            int m = lg * 4 + rg;
            float g  = 1.f / (1.f + __expf(-accD[rg]));
            float h0 = ldsR1(Hb + ti * 4096,        m, nD);
            float h1 = ldsR1(Hb + ti * 4096 + 2048, m, nD);
            ldsW1(FX + ti * 2048, m, nD, f2bf((1.f - g) * h0 + g * h1));
        }
    }
    __syncthreads();   // t2

    // fix norms: 80 rows over 32 row-slots x 16 lanes
    {
        int rr = tid >> 4, sl = tid & 15;
        #pragma unroll
        for (int j = 0; j < 3; ++j) {
            int rs = j * 32 + rr;
            if (rs < 80) {
                int ti = rs >> 4, r = rs & 15;
                bf16x8 v = ldsAx(FX + ti * 2048, r, sl * 16, 256);
                float ss = 0.f;
                #pragma unroll
                for (int jj = 0; jj < 8; ++jj) { float f = (float)v[jj]; ss += f * f; }
                ss += __shfl_xor(ss, 1); ss += __shfl_xor(ss, 2);
                ss += __shfl_xor(ss, 4); ss += __shfl_xor(ss, 8);
                if (sl == 0) scl2s[ti][r] = (ss > 0.f) ? (1.f / sqrtf(ss)) : 0.f;
            }
        }
    }
    __syncthreads();   // t3

    // stage E: all 5 tiles (waves 0..4); LOG aliases Hb (dead after D)
    if (w < 5) {
        const bool live = (ccE < NCLASS);
        bf16x8 bfz;
        #pragma unroll
        for (int j = 0; j < 8; ++j) bfz[j] = (__bf16)0.f;
        #pragma unroll
        for (int ti = 0; ti < 5; ++ti) {
            f32x4 accE = zero4;
            #pragma unroll
            for (int kc = 0; kc < 4; ++kc) {
                bf16x8 a = ldsAx(FX + ti * 2048, ln, kc * 64 + lg * 16, 256);
                accE = MFMA(a, live ? wcf[kc] : bfz, accE);
            }
            if (live) {
                float* LO = LOGb + ti * 1280;
                #pragma unroll
                for (int rg = 0; rg < 4; ++rg) {
                    int m = lg * 4 + rg;
                    LO[m * 80 + ccE] = fmaxf(accE[rg] * scl2s[ti][m], 0.f);
                }
            }
        }
    }
    __syncthreads();   // t4

    // log_softmax + store: 80 rows over 32 row-slots x 16 lanes, 5 classes/lane
    {
        int rr = tid >> 4, l16 = tid & 15;
        #pragma unroll
        for (int j = 0; j < 3; ++j) {
            int rs = j * 32 + rr;
            if (rs < 80) {
                int ti = rs >> 4, r = rs & 15;
                const float* LO = LOGb + ti * 1280 + r * 80;
                float v[5];
                #pragma unroll
                for (int jj = 0; jj < 5; ++jj) {
                    int c = l16 + jj * 16;
                    v[jj] = (c < NCLASS) ? LO[c] : -1e30f;
                }
                float mx = v[0];
                #pragma unroll
                for (int jj = 1; jj < 5; ++jj) mx = fmaxf(mx, v[jj]);
                mx = fmaxf(mx, __shfl_xor(mx, 1)); mx = fmaxf(mx, __shfl_xor(mx, 2));
                mx = fmaxf(mx, __shfl_xor(mx, 4)); mx = fmaxf(mx, __shfl_xor(mx, 8));
                float se = 0.f;
                #pragma unroll
                for (int jj = 0; jj < 5; ++jj) {
                    int c = l16 + jj * 16;
                    if (c < NCLASS) se += __expf(v[jj] - mx);
                }
                se += __shfl_xor(se, 1); se += __shfl_xor(se, 2);
                se += __shfl_xor(se, 4); se += __shfl_xor(se, 8);
                float lz = mx + __logf(se);
                size_t orow = (size_t)(tile0 + ti) * 16 + r;
                #pragma unroll
                for (int jj = 0; jj < 5; ++jj) {
                    int c = l16 + jj * 16;
                    if (c < NCLASS) out[orow * NCLASS + c] = v[jj] - lz;
                }
            }
        }
    }
}

// ---- fallback (ws too small): fused kernel, f32 weights inline ----
static __device__ __forceinline__ bf16x8 bfragF(const float* p, size_t off) {
    const float4* q = (const float4*)(p + off);
    return pack8(q[0], q[1]);
}
__global__ __launch_bounds__(512) void hyper_fb(
    const float* __restrict__ x, const float* __restrict__ sf,
    const int* __restrict__ idx,
    const float* __restrict__ W0, const float* __restrict__ W1,
    const float* __restrict__ G1, const float* __restrict__ G2,
    const float* __restrict__ GT, const float* __restrict__ Wc,
    float* __restrict__ out)
{
    __shared__ __align__(16) unsigned short Xbuf[2][16][NFEAT];
    __shared__ __align__(16) unsigned short Hbuf[2][16][NHID];
    __shared__ float scl2[16];
    unsigned short* G12 = &Xbuf[0][0][0];
    unsigned short* FIX = &Xbuf[0][0][0] + 4096;
    float*          LOG = (float*)(&Xbuf[0][0][0] + 6144);

    const int tid = threadIdx.x, bid = blockIdx.x;
    const int w = tid >> 6, lane = tid & 63;
    const int ln = lane & 15, lg = lane >> 4;
    const int tB = w >> 2, nq = w & 3;
    const f32x4 zero4 = {0.f, 0.f, 0.f, 0.f};

    {
        char* xb = (char*)&Xbuf[0][0][0];
        #pragma unroll
        for (int j = 0; j < 4; ++j) {
            int p = w * 4 + j, t = p >> 4, m = p & 15;
            int ri = idx[bid * 16 + m];
            const float4* q = (const float4*)((t ? sf : x) + (size_t)ri * NFEAT + lane * 8);
            float4 a = q[0], b = q[1];
            float ss = a.x*a.x + a.y*a.y + a.z*a.z + a.w*a.w
                     + b.x*b.x + b.y*b.y + b.z*b.z + b.w*b.w;
            #pragma unroll
            for (int d = 1; d < 64; d <<= 1) ss += __shfl_xor(ss, d);
            float scl = (ss > 0.f) ? (1.f / sqrtf(ss)) : 0.f;
            int soff = t * 16384 + m * 1024 + ((lane * 16) ^ ((m & 7) << 4));
            *(bf16x8*)(xb + soff) = pack8s(a, b, scl);
        }
    }
    __syncthreads();
    {
        const float* Wp = tB ? W1 : W0;
        f32x4 acc0 = zero4, acc1 = zero4;
        const unsigned short* Xb = (const unsigned short*)((const char*)&Xbuf[0][0][0] + tB * 16384);
        #pragma unroll
        for (int kc = 0; kc < 16; ++kc) {
            bf16x8 a = ldsAx(Xb, ln, kc * 64 + lg * 16, 1024);
            acc0 = MFMA(a, bfragF(Wp, (size_t)(nq * 32 + ln) * NFEAT + kc * 32 + lg * 8), acc0);
            acc1 = MFMA(a, bfragF(Wp, (size_t)(nq * 32 + 16 + ln) * NFEAT + kc * 32 + lg * 8), acc1);
        }
        unsigned short* Hb = &Hbuf[tB][0][0];
        #pragma unroll
        for (int rg = 0; rg < 4; ++rg) {
            int m = lg * 4 + rg;
            ldsW1(Hb, m, nq * 32 + ln,      f2bf(fmaxf(acc0[rg], 0.f)));
            ldsW1(Hb, m, nq * 32 + 16 + ln, f2bf(fmaxf(acc1[rg], 0.f)));
        }
    }
    __syncthreads();
    {
        const float* Gp = tB ? G2 : G1;
        const unsigned short* Hs = &Hbuf[tB][0][0];
        f32x4 accC[2] = {zero4, zero4};
        #pragma unroll
        for (int kc = 0; kc < 4; ++kc) {
            bf16x8 a = ldsAx(Hs, ln, kc * 64 + lg * 16, 256);
            accC[0] = MFMA(a, bfragF(Gp, (size_t)(nq * 32 + ln) * NHID + kc * 32 + lg * 8), accC[0]);
            accC[1] = MFMA(a, bfragF(Gp, (size_t)(nq * 32 + 16 + ln) * NHID + kc * 32 + lg * 8), accC[1]);
        }
        unsigned short* Gd = G12 + tB * 2048;
        #pragma unroll
        for (int nt = 0; nt < 2; ++nt)
            #pragma unroll
            for (int rg = 0; rg < 4; ++rg) {
                int m = lg * 4 + rg;
                ldsW1(Gd, m, nq * 32 + nt * 16 + ln, f2bf(accC[nt][rg]));
            }
    }
    __syncthreads();
    {
        f32x4 accD = zero4;
        const int n = w * 16 + ln;
        #pragma unroll
        for (int kc = 0; kc < 8; ++kc) {
            const unsigned short* As = G12 + (kc >> 2) * 2048;
            bf16x8 a = ldsAx(As, ln, (kc & 3) * 64 + lg * 16, 256);
            accD = MFMA(a, bfragF(GT, (size_t)n * (2 * NHID) + kc * 32 + lg * 8), accD);
        }
        #pragma unroll
        for (int rg = 0; rg < 4; ++rg) {
            int m = lg * 4 + rg;
            float g  = 1.f / (1.f + __expf(-accD[rg]));
            float h0 = ldsR1(&Hbuf[0][0][0], m, n);
            float h1 = ldsR1(&Hbuf[1][0][0], m, n);
            ldsW1(FIX, m, n, f2bf((1.f - g) * h0 + g * h1));
        }
    }
    __syncthreads();
    if (tid < 256) {
        int r = tid >> 4, sl = tid & 15;
        bf16x8 v = ldsAx(FIX, r, sl * 16, 256);
        float ss = 0.f;
        #pragma unroll
        for (int j = 0; j < 8; ++j) { float f = (float)v[j]; ss += f * f; }
        ss += __shfl_xor(ss, 1); ss += __shfl_xor(ss, 2);
        ss += __shfl_xor(ss, 4); ss += __shfl_xor(ss, 8);
        if (sl == 0) scl2[r] = (ss > 0.f) ? (1.f / sqrtf(ss)) : 0.f;
    }
    __syncthreads();
    if (w < 5) {
        const int cc = w * 16 + ln;
        bf16x8 bfz;
        #pragma unroll
        for (int j = 0; j < 8; ++j) bfz[j] = (__bf16)0.f;
        f32x4 accE = zero4;
        #pragma unroll
        for (int kc = 0; kc < 4; ++kc) {
            bf16x8 a = ldsAx(FIX, ln, kc * 64 + lg * 16, 256);
            bf16x8 b = (cc < NCLASS) ? bfragF(Wc, (size_t)cc * NHID + kc * 32 + lg * 8) : bfz;
            accE = MFMA(a, b, accE);
        }
        #pragma unroll
        for (int rg = 0; rg < 4; ++rg) {
            int m = lg * 4 + rg;
            float v = fmaxf(accE[rg] * scl2[m], 0.f);
            LOG[m * 80 + cc] = (cc < NCLASS) ? v : -1e30f;
        }
    }
    __syncthreads();
    {
        const int r = tid >> 5, l32 = tid & 31;
        float v0 = LOG[r * 80 + l32];
        float v1 = LOG[r * 80 + 32 + l32];
        float v2 = (l32 < 16) ? LOG[r * 80 + 64 + l32] : -1e30f;
        float mx = fmaxf(fmaxf(v0, v1), v2);
        #pragma unroll
        for (int d = 1; d < 32; d <<= 1) mx = fmaxf(mx, __shfl_xor(mx, d, 32));
        float se = __expf(v0 - mx) + __expf(v1 - mx) + ((l32 < 16) ? __expf(v2 - mx) : 0.f);
        #pragma unroll
        for (int d = 1; d < 32; d <<= 1) se += __shfl_xor(se, d, 32);
        float lz = mx + __logf(se);
        size_t orow = (size_t)bid * 16 + r;
        out[orow * NCLASS + l32] = v0 - lz;
        if (l32 + 32 < NCLASS) out[orow * NCLASS + 32 + l32] = v1 - lz;
        if (l32 + 64 < NCLASS) out[orow * NCLASS + 64 + l32] = v2 - lz;
    }
}

extern "C" void kernel_launch(void* const* d_in, const int* in_sizes, int n_in,
                              void* d_out, int out_size, void* d_ws, size_t ws_size,
                              hipStream_t stream)
{
    const float* x   = (const float*)d_in[0];
    const float* sf  = (const float*)d_in[1];
    const int*   idx = (const int*)d_in[2];
    const float* W0  = (const float*)d_in[3];
    const float* W1  = (const float*)d_in[4];
    const float* G1  = (const float*)d_in[5];
    const float* G2  = (const float*)d_in[6];
    const float* GT  = (const float*)d_in[7];
    const float* Wc  = (const float*)d_in[8];
    float* out = (float*)d_out;

    if (ws_size >= WS_NEED) {
        unsigned short* wsH     = (unsigned short*)d_ws;
        unsigned short* wsG     = wsH + HELEMS;
        unsigned short* wsWimg  = wsG + GELEMS;
        unsigned short* wsSmall = wsWimg + WIMG_ELEMS;
        prep_weights<<<dim3(137), dim3(256), 0, stream>>>(W0, W1, G1, G2, GT, Wc, wsWimg, wsSmall);
        stageBC<<<dim3(250), dim3(512), 0, stream>>>(x, sf, idx, wsWimg, wsSmall, wsH, wsG);
        tailDE5<<<dim3(125), dim3(512), 0, stream>>>(wsSmall, wsH, wsG, out);
    } else {
        hyper_fb<<<dim3(NTILE), dim3(512), 0, stream>>>(
            x, sf, idx, W0, W1, G1, G2, GT, Wc, out);
    }
}

// Round 15
// 36.808 us; speedup vs baseline: 2.6690x; 1.0059x over previous
//
#include <hip/hip_runtime.h>
#include <math.h>

#define NFEAT  512
#define NHID   128
#define NCLASS 70
#define NIDX   10000
#define NTILE  625
#define HELEMS (2u * NIDX * NHID)          // 2,560,000 ushorts: H scratch
#define GELEMS (2u * NIDX * NHID)          // 2,560,000 ushorts: G12 scratch
#define WFRAG_ELEMS (2u * 128 * 512)       // 131,072 ushorts: W0/W1 fragment-major
#define SMALL_ELEMS 74496u                 // G1,G2,GT,Wc row-major bf16
#define WS_NEED ((size_t)(HELEMS + GELEMS + WFRAG_ELEMS + SMALL_ELEMS) * 2)

typedef float  f32x4  __attribute__((ext_vector_type(4)));
typedef __bf16 bf16x8 __attribute__((ext_vector_type(8)));

static __device__ __forceinline__ unsigned short f2bf(float f) {
    unsigned u = __builtin_bit_cast(unsigned, f);
    u += 0x7fffu + ((u >> 16) & 1u);
    return (unsigned short)(u >> 16);
}
static __device__ __forceinline__ float bf2f(unsigned short h) {
    unsigned u = ((unsigned)h) << 16;
    return __builtin_bit_cast(float, u);
}
static __device__ __forceinline__ bf16x8 pack8(float4 a, float4 b) {
    bf16x8 r;
    r[0] = (__bf16)a.x; r[1] = (__bf16)a.y; r[2] = (__bf16)a.z; r[3] = (__bf16)a.w;
    r[4] = (__bf16)b.x; r[5] = (__bf16)b.y; r[6] = (__bf16)b.z; r[7] = (__bf16)b.w;
    return r;
}
static __device__ __forceinline__ bf16x8 pack8s(float4 a, float4 b, float s) {
    bf16x8 r;
    r[0] = (__bf16)(a.x * s); r[1] = (__bf16)(a.y * s); r[2] = (__bf16)(a.z * s); r[3] = (__bf16)(a.w * s);
    r[4] = (__bf16)(b.x * s); r[5] = (__bf16)(b.y * s); r[6] = (__bf16)(b.z * s); r[7] = (__bf16)(b.w * s);
    return r;
}
static __device__ __forceinline__ f32x4 MFMA(bf16x8 a, bf16x8 b, f32x4 c) {
    return __builtin_amdgcn_mfma_f32_16x16x32_bf16(a, b, c, 0, 0, 0);
}
static __device__ __forceinline__ bf16x8 ldsAx(const unsigned short* base, int row, int colb, int rstride) {
    return *(const bf16x8*)((const char*)base + row * rstride + (colb ^ ((row & 7) << 4)));
}
static __device__ __forceinline__ void ldsW1(unsigned short* base, int row, int col, unsigned short v) {
    *(unsigned short*)((char*)base + row * 256 + ((col * 2) ^ ((row & 7) << 4))) = v;
}
static __device__ __forceinline__ float ldsR1(const unsigned short* base, int row, int col) {
    return bf2f(*(const unsigned short*)((const char*)base + row * 256 + ((col * 2) ^ ((row & 7) << 4))));
}

// ---- prep: W0/W1 -> FRAGMENT-MAJOR bf16 (wave-coalesced); G1/G2/GT/Wc -> bf16 ----
// fragment layout: [(t*8+w)*16 + kc][lane] of bf16x8; fragment value =
// W_t[w*16 + (lane&15)][kc*32 + (lane>>4)*8 .. +8]
__global__ void prep_weights(const float* __restrict__ W0, const float* __restrict__ W1,
                             const float* __restrict__ G1, const float* __restrict__ G2,
                             const float* __restrict__ GT, const float* __restrict__ Wc,
                             unsigned short* __restrict__ wsWfrag,
                             unsigned short* __restrict__ wsSmall) {
    int i = blockIdx.x * 256 + threadIdx.x;
    if (i < 16384) {
        int t = i >> 13;
        int r = i & 8191;
        int w = r >> 10, kc = (r >> 6) & 15, lane = r & 63;
        int n   = w * 16 + (lane & 15);
        int col = kc * 32 + (lane >> 4) * 8;
        const float* src = (t ? W1 : W0) + (size_t)n * NFEAT + col;
        float4 a = ((const float4*)src)[0], b = ((const float4*)src)[1];
        *(bf16x8*)(wsWfrag + (size_t)i * 8) = pack8(a, b);
    } else {
        int i4 = i - 16384;
        if (i4 >= 18624) return;
        const float* src; int base4, dstb;
        if      (i4 < 4096)  { src = G1; base4 = 0;     dstb = 0; }
        else if (i4 < 8192)  { src = G2; base4 = 4096;  dstb = 16384; }
        else if (i4 < 16384) { src = GT; base4 = 8192;  dstb = 32768; }
        else                 { src = Wc; base4 = 16384; dstb = 65536; }
        float4 v = ((const float4*)src)[i4 - base4];
        ushort4 o;
        o.x = f2bf(v.x); o.y = f2bf(v.y); o.z = f2bf(v.z); o.w = f2bf(v.w);
        *(ushort4*)(wsSmall + dstb + (size_t)(i4 - base4) * 4) = o;
    }
}

// ---- stage B+C, W in REGISTERS: 1250 short blocks (t,tile), 24 KB LDS ----
__global__ __launch_bounds__(512) void stageBC_reg(
    const float* __restrict__ x, const float* __restrict__ sf,
    const int* __restrict__ idx,
    const unsigned short* __restrict__ wsWfrag,
    const unsigned short* __restrict__ wsSmall,
    unsigned short* __restrict__ wsH,
    unsigned short* __restrict__ wsG)
{
    __shared__ __align__(16) unsigned short Xl[8192];   // 16 KB swizzled X tile
    __shared__ __align__(16) unsigned short Hl[2048];   // 4 KB swizzled H tile
    __shared__ __align__(16) unsigned short Gl[2048];   // 4 KB swizzled G12 tile

    const int tid  = threadIdx.x;
    const int w    = tid >> 6;          // wave 0..7 -> output cols w*16..+15
    const int lane = tid & 63;
    const int ln   = lane & 15, lg = lane >> 4;
    const int bid  = blockIdx.x;
    const int t    = bid & 1, tile = bid >> 1;
    const float* XS = t ? sf : x;
    const f32x4 zero4 = {0.f, 0.f, 0.f, 0.f};

    // gather volley: wave w owns rows w and w+8 — longest latency, issue first
    float4 ga0, ga1, gb0, gb1;
    {
        int r0 = idx[tile * 16 + w];
        int r1 = idx[tile * 16 + w + 8];
        const float4* p0 = (const float4*)(XS + (size_t)r0 * NFEAT + lane * 8);
        const float4* p1 = (const float4*)(XS + (size_t)r1 * NFEAT + lane * 8);
        ga0 = p0[0]; ga1 = p0[1];
        gb0 = p1[0]; gb1 = p1[1];
    }
    // W fragments -> registers: 16 perfectly-coalesced 16B/lane loads (L2)
    bf16x8 wf[16];
    {
        const unsigned short* wb = wsWfrag + ((size_t)(t * 8 + w) * 16) * 512 + lane * 8;
        #pragma unroll
        for (int kc = 0; kc < 16; ++kc)
            wf[kc] = *(const bf16x8*)(wb + kc * 512);
    }
    // stage-C fragments for this tensor
    bf16x8 cf[4];
    {
        const unsigned short* Gsm = wsSmall + t * 16384;   // G1 or G2 bf16
        #pragma unroll
        for (int kc = 0; kc < 4; ++kc)
            cf[kc] = *(const bf16x8*)(Gsm + (size_t)(w * 16 + ln) * NHID + kc * 32 + lg * 8);
    }
    // norm + swizzled bf16 store of X rows
    auto putX = [&](int m, float4 a, float4 b) {
        float ss = a.x*a.x + a.y*a.y + a.z*a.z + a.w*a.w
                 + b.x*b.x + b.y*b.y + b.z*b.z + b.w*b.w;
        #pragma unroll
        for (int d = 1; d < 64; d <<= 1) ss += __shfl_xor(ss, d);
        float scl = (ss > 0.f) ? (1.f / sqrtf(ss)) : 0.f;
        *(bf16x8*)((char*)Xl + m * 1024 + ((lane * 16) ^ ((m & 7) << 4))) = pack8s(a, b, scl);
    };
    putX(w,     ga0, ga1);
    putX(w + 8, gb0, gb1);
    __syncthreads();   // b1: Xl ready

    // stage B: 16 ds_read (X only) + 16 MFMA, W from registers
    {
        f32x4 accE = zero4, accO = zero4;
        #pragma unroll
        for (int kc = 0; kc < 16; ++kc) {
            bf16x8 a = ldsAx(Xl, ln, kc * 64 + lg * 16, 1024);
            if (kc & 1) accO = MFMA(a, wf[kc], accO); else accE = MFMA(a, wf[kc], accE);
        }
        f32x4 acc = accE + accO;
        #pragma unroll
        for (int rg = 0; rg < 4; ++rg)
            ldsW1(Hl, lg * 4 + rg, w * 16 + ln, f2bf(fmaxf(acc[rg], 0.f)));
    }
    __syncthreads();   // b2: Hl ready

    // stage C (reads Hl) + H copy to ws (concurrent)
    {
        f32x4 aC = zero4;
        #pragma unroll
        for (int kc = 0; kc < 4; ++kc) {
            bf16x8 a = ldsAx(Hl, ln, kc * 64 + lg * 16, 256);
            aC = MFMA(a, cf[kc], aC);
        }
        if (tid < 256) {
            ((uint4*)(wsH + ((size_t)t * NIDX + (size_t)tile * 16) * NHID))[tid]
                = ((const uint4*)Hl)[tid];
        }
        #pragma unroll
        for (int rg = 0; rg < 4; ++rg)
            ldsW1(Gl, lg * 4 + rg, w * 16 + ln, f2bf(aC[rg]));
    }
    __syncthreads();   // b3: Gl ready

    if (tid < 256) {
        ((uint4*)(wsG + ((size_t)t * NIDX + (size_t)tile * 16) * NHID))[tid]
            = ((const uint4*)Gl)[tid];
    }
}

// ---- tail: 125 blocks x 5 tiles; stages D/E + softmax (r14, proven) ----
__global__ __launch_bounds__(512) void tailDE5(
    const unsigned short* __restrict__ wsSmall,
    const unsigned short* __restrict__ wsH,
    const unsigned short* __restrict__ wsG,
    float* __restrict__ out)
{
    __shared__ __align__(16) char SM[102400];  // Hb 40K | Gb 40K | FX 20K ; LOG aliases Hb
    __shared__ float scl2s[5][16];

    unsigned short* Hb = (unsigned short*)SM;              // [5][2][16][128]
    unsigned short* Gb = (unsigned short*)(SM + 40960);    // [5][2][16][128]
    unsigned short* FX = (unsigned short*)(SM + 81920);    // [5][16][128]
    float* LOGb = (float*)SM;                              // [5][16][80] aliases Hb after D

    const unsigned short* GTp = wsSmall + 32768;
    const unsigned short* Wcp = wsSmall + 65536;

    const int tid  = threadIdx.x;
    const int w    = tid >> 6;
    const int lane = tid & 63;
    const int ln   = lane & 15, lg = lane >> 4;
    const int tile0 = blockIdx.x * 5;
    const f32x4 zero4 = {0.f, 0.f, 0.f, 0.f};

    #pragma unroll
    for (int i = 0; i < 5; ++i) {
        int q = tid + i * 512;
        int seg = q >> 8, r = q & 255;
        int ti = seg >> 1, tt = seg & 1;
        size_t off = ((size_t)tt * NIDX + (size_t)(tile0 + ti) * 16) * NHID;
        ((uint4*)Hb)[q] = ((const uint4*)(wsH + off))[r];
        ((uint4*)Gb)[q] = ((const uint4*)(wsG + off))[r];
    }
    const int nD = w * 16 + ln;
    bf16x8 gt[8];
    #pragma unroll
    for (int kc = 0; kc < 8; ++kc)
        gt[kc] = *(const bf16x8*)(GTp + (size_t)nD * (2 * NHID) + kc * 32 + lg * 8);
    const int ccE = nD;
    const int ccl = (ccE < NCLASS) ? ccE : 0;
    bf16x8 wcf[4];
    #pragma unroll
    for (int kc = 0; kc < 4; ++kc)
        wcf[kc] = *(const bf16x8*)(Wcp + (size_t)ccl * NHID + kc * 32 + lg * 8);
    __syncthreads();   // t1

    #pragma unroll
    for (int ti = 0; ti < 5; ++ti) {
        f32x4 aE = zero4, aO = zero4;
        #pragma unroll
        for (int kc = 0; kc < 8; ++kc) {
            const unsigned short* As = Gb + ti * 4096 + (kc >> 2) * 2048;
            bf16x8 a = ldsAx(As, ln, (kc & 3) * 64 + lg * 16, 256);
            if (kc & 1) aO = MFMA(a, gt[kc], aO); else aE = MFMA(a, gt[kc], aE);
        }
        f32x4 accD = aE + aO;
        #pragma unroll
        for (int rg = 0; rg < 4; ++rg) {
            int m = lg * 4 + rg;
            float g  = 1.f / (1.f + __expf(-accD[rg]));
            float h0 = ldsR1(Hb + ti * 4096,        m, nD);
            float h1 = ldsR1(Hb + ti * 4096 + 2048, m, nD);
            ldsW1(FX + ti * 2048, m, nD, f2bf((1.f - g) * h0 + g * h1));
        }
    }
    __syncthreads();   // t2

    {
        int rr = tid >> 4, sl = tid & 15;
        #pragma unroll
        for (int j = 0; j < 3; ++j) {
            int rs = j * 32 + rr;
            if (rs < 80) {
                int ti = rs >> 4, r = rs & 15;
                bf16x8 v = ldsAx(FX + ti * 2048, r, sl * 16, 256);
                float ss = 0.f;
                #pragma unroll
                for (int jj = 0; jj < 8; ++jj) { float f = (float)v[jj]; ss += f * f; }
                ss += __shfl_xor(ss, 1); ss += __shfl_xor(ss, 2);
                ss += __shfl_xor(ss, 4); ss += __shfl_xor(ss, 8);
                if (sl == 0) scl2s[ti][r] = (ss > 0.f) ? (1.f / sqrtf(ss)) : 0.f;
            }
        }
    }
    __syncthreads();   // t3

    if (w < 5) {
        const bool live = (ccE < NCLASS);
        bf16x8 bfz;
        #pragma unroll
        for (int j = 0; j < 8; ++j) bfz[j] = (__bf16)0.f;
        #pragma unroll
        for (int ti = 0; ti < 5; ++ti) {
            f32x4 accE = zero4;
            #pragma unroll
            for (int kc = 0; kc < 4; ++kc) {
                bf16x8 a = ldsAx(FX + ti * 2048, ln, kc * 64 + lg * 16, 256);
                accE = MFMA(a, live ? wcf[kc] : bfz, accE);
            }
            if (live) {
                float* LO = LOGb + ti * 1280;
                #pragma unroll
                for (int rg = 0; rg < 4; ++rg) {
                    int m = lg * 4 + rg;
                    LO[m * 80 + ccE] = fmaxf(accE[rg] * scl2s[ti][m], 0.f);
                }
            }
        }
    }
    __syncthreads();   // t4

    {
        int rr = tid >> 4, l16 = tid & 15;
        #pragma unroll
        for (int j = 0; j < 3; ++j) {
            int rs = j * 32 + rr;
            if (rs < 80) {
                int ti = rs >> 4, r = rs & 15;
                const float* LO = LOGb + ti * 1280 + r * 80;
                float v[5];
                #pragma unroll
                for (int jj = 0; jj < 5; ++jj) {
                    int c = l16 + jj * 16;
                    v[jj] = (c < NCLASS) ? LO[c] : -1e30f;
                }
                float mx = v[0];
                #pragma unroll
                for (int jj = 1; jj < 5; ++jj) mx = fmaxf(mx, v[jj]);
                mx = fmaxf(mx, __shfl_xor(mx, 1)); mx = fmaxf(mx, __shfl_xor(mx, 2));
                mx = fmaxf(mx, __shfl_xor(mx, 4)); mx = fmaxf(mx, __shfl_xor(mx, 8));
                float se = 0.f;
                #pragma unroll
                for (int jj = 0; jj < 5; ++jj) {
                    int c = l16 + jj * 16;
                    if (c < NCLASS) se += __expf(v[jj] - mx);
                }
                se += __shfl_xor(se, 1); se += __shfl_xor(se, 2);
                se += __shfl_xor(se, 4); se += __shfl_xor(se, 8);
                float lz = mx + __logf(se);
                size_t orow = (size_t)(tile0 + ti) * 16 + r;
                #pragma unroll
                for (int jj = 0; jj < 5; ++jj) {
                    int c = l16 + jj * 16;
                    if (c < NCLASS) out[orow * NCLASS + c] = v[jj] - lz;
                }
            }
        }
    }
}

// ---- fallback (ws too small): fused kernel, f32 weights inline ----
static __device__ __forceinline__ bf16x8 bfragF(const float* p, size_t off) {
    const float4* q = (const float4*)(p + off);
    return pack8(q[0], q[1]);
}
__global__ __launch_bounds__(512) void hyper_fb(
    const float* __restrict__ x, const float* __restrict__ sf,
    const int* __restrict__ idx,
    const float* __restrict__ W0, const float* __restrict__ W1,
    const float* __restrict__ G1, const float* __restrict__ G2,
    const float* __restrict__ GT, const float* __restrict__ Wc,
    float* __restrict__ out)
{
    __shared__ __align__(16) unsigned short Xbuf[2][16][NFEAT];
    __shared__ __align__(16) unsigned short Hbuf[2][16][NHID];
    __shared__ float scl2[16];
    unsigned short* G12 = &Xbuf[0][0][0];
    unsigned short* FIX = &Xbuf[0][0][0] + 4096;
    float*          LOG = (float*)(&Xbuf[0][0][0] + 6144);

    const int tid = threadIdx.x, bid = blockIdx.x;
    const int w = tid >> 6, lane = tid & 63;
    const int ln = lane & 15, lg = lane >> 4;
    const int tB = w >> 2, nq = w & 3;
    const f32x4 zero4 = {0.f, 0.f, 0.f, 0.f};

    {
        char* xb = (char*)&Xbuf[0][0][0];
        #pragma unroll
        for (int j = 0; j < 4; ++j) {
            int p = w * 4 + j, t = p >> 4, m = p & 15;
            int ri = idx[bid * 16 + m];
            const float4* q = (const float4*)((t ? sf : x) + (size_t)ri * NFEAT + lane * 8);
            float4 a = q[0], b = q[1];
            float ss = a.x*a.x + a.y*a.y + a.z*a.z + a.w*a.w
                     + b.x*b.x + b.y*b.y + b.z*b.z + b.w*b.w;
            #pragma unroll
            for (int d = 1; d < 64; d <<= 1) ss += __shfl_xor(ss, d);
            float scl = (ss > 0.f) ? (1.f / sqrtf(ss)) : 0.f;
            int soff = t * 16384 + m * 1024 + ((lane * 16) ^ ((m & 7) << 4));
            *(bf16x8*)(xb + soff) = pack8s(a, b, scl);
        }
    }
    __syncthreads();
    {
        const float* Wp = tB ? W1 : W0;
        f32x4 acc0 = zero4, acc1 = zero4;
        const unsigned short* Xb = (const unsigned short*)((const char*)&Xbuf[0][0][0] + tB * 16384);
        #pragma unroll
        for (int kc = 0; kc < 16; ++kc) {
            bf16x8 a = ldsAx(Xb, ln, kc * 64 + lg * 16, 1024);
            acc0 = MFMA(a, bfragF(Wp, (size_t)(nq * 32 + ln) * NFEAT + kc * 32 + lg * 8), acc0);
            acc1 = MFMA(a, bfragF(Wp, (size_t)(nq * 32 + 16 + ln) * NFEAT + kc * 32 + lg * 8), acc1);
        }
        unsigned short* Hb = &Hbuf[tB][0][0];
        #pragma unroll
        for (int rg = 0; rg < 4; ++rg) {
            int m = lg * 4 + rg;
            ldsW1(Hb, m, nq * 32 + ln,      f2bf(fmaxf(acc0[rg], 0.f)));
            ldsW1(Hb, m, nq * 32 + 16 + ln, f2bf(fmaxf(acc1[rg], 0.f)));
        }
    }
    __syncthreads();
    {
        const float* Gp = tB ? G2 : G1;
        const unsigned short* Hs = &Hbuf[tB][0][0];
        f32x4 accC[2] = {zero4, zero4};
        #pragma unroll
        for (int kc = 0; kc < 4; ++kc) {
            bf16x8 a = ldsAx(Hs, ln, kc * 64 + lg * 16, 256);
            accC[0] = MFMA(a, bfragF(Gp, (size_t)(nq * 32 + ln) * NHID + kc * 32 + lg * 8), accC[0]);
            accC[1] = MFMA(a, bfragF(Gp, (size_t)(nq * 32 + 16 + ln) * NHID + kc * 32 + lg * 8), accC[1]);
        }
        unsigned short* Gd = G12 + tB * 2048;
        #pragma unroll
        for (int nt = 0; nt < 2; ++nt)
            #pragma unroll
            for (int rg = 0; rg < 4; ++rg) {
                int m = lg * 4 + rg;
                ldsW1(Gd, m, nq * 32 + nt * 16 + ln, f2bf(accC[nt][rg]));
            }
    }
    __syncthreads();
    {
        f32x4 accD = zero4;
        const int n = w * 16 + ln;
        #pragma unroll
        for (int kc = 0; kc < 8; ++kc) {
            const unsigned short* As = G12 + (kc >> 2) * 2048;
            bf16x8 a = ldsAx(As, ln, (kc & 3) * 64 + lg * 16, 256);
            accD = MFMA(a, bfragF(GT, (size_t)n * (2 * NHID) + kc * 32 + lg * 8), accD);
        }
        #pragma unroll
        for (int rg = 0; rg < 4; ++rg) {
            int m = lg * 4 + rg;
            float g  = 1.f / (1.f + __expf(-accD[rg]));
            float h0 = ldsR1(&Hbuf[0][0][0], m, n);
            float h1 = ldsR1(&Hbuf[1][0][0], m, n);
            ldsW1(FIX, m, n, f2bf((1.f - g) * h0 + g * h1));
        }
    }
    __syncthreads();
    if (tid < 256) {
        int r = tid >> 4, sl = tid & 15;
        bf16x8 v = ldsAx(FIX, r, sl * 16, 256);
        float ss = 0.f;
        #pragma unroll
        for (int j = 0; j < 8; ++j) { float f = (float)v[j]; ss += f * f; }
        ss += __shfl_xor(ss, 1); ss += __shfl_xor(ss, 2);
        ss += __shfl_xor(ss, 4); ss += __shfl_xor(ss, 8);
        if (sl == 0) scl2[r] = (ss > 0.f) ? (1.f / sqrtf(ss)) : 0.f;
    }
    __syncthreads();
    if (w < 5) {
        const int cc = w * 16 + ln;
        bf16x8 bfz;
        #pragma unroll
        for (int j = 0; j < 8; ++j) bfz[j] = (__bf16)0.f;
        f32x4 accE = zero4;
        #pragma unroll
        for (int kc = 0; kc < 4; ++kc) {
            bf16x8 a = ldsAx(FIX, ln, kc * 64 + lg * 16, 256);
            bf16x8 b = (cc < NCLASS) ? bfragF(Wc, (size_t)cc * NHID + kc * 32 + lg * 8) : bfz;
            accE = MFMA(a, b, accE);
        }
        #pragma unroll
        for (int rg = 0; rg < 4; ++rg) {
            int m = lg * 4 + rg;
            float v = fmaxf(accE[rg] * scl2[m], 0.f);
            LOG[m * 80 + cc] = (cc < NCLASS) ? v : -1e30f;
        }
    }
    __syncthreads();
    {
        const int r = tid >> 5, l32 = tid & 31;
        float v0 = LOG[r * 80 + l32];
        float v1 = LOG[r * 80 + 32 + l32];
        float v2 = (l32 < 16) ? LOG[r * 80 + 64 + l32] : -1e30f;
        float mx = fmaxf(fmaxf(v0, v1), v2);
        #pragma unroll
        for (int d = 1; d < 32; d <<= 1) mx = fmaxf(mx, __shfl_xor(mx, d, 32));
        float se = __expf(v0 - mx) + __expf(v1 - mx) + ((l32 < 16) ? __expf(v2 - mx) : 0.f);
        #pragma unroll
        for (int d = 1; d < 32; d <<= 1) se += __shfl_xor(se, d, 32);
        float lz = mx + __logf(se);
        size_t orow = (size_t)bid * 16 + r;
        out[orow * NCLASS + l32] = v0 - lz;
        if (l32 + 32 < NCLASS) out[orow * NCLASS + 32 + l32] = v1 - lz;
        if (l32 + 64 < NCLASS) out[orow * NCLASS + 64 + l32] = v2 - lz;
    }
}

extern "C" void kernel_launch(void* const* d_in, const int* in_sizes, int n_in,
                              void* d_out, int out_size, void* d_ws, size_t ws_size,
                              hipStream_t stream)
{
    const float* x   = (const float*)d_in[0];
    const float* sf  = (const float*)d_in[1];
    const int*   idx = (const int*)d_in[2];
    const float* W0  = (const float*)d_in[3];
    const float* W1  = (const float*)d_in[4];
    const float* G1  = (const float*)d_in[5];
    const float* G2  = (const float*)d_in[6];
    const float* GT  = (const float*)d_in[7];
    const float* Wc  = (const float*)d_in[8];
    float* out = (float*)d_out;

    if (ws_size >= WS_NEED) {
        unsigned short* wsH     = (unsigned short*)d_ws;
        unsigned short* wsG     = wsH + HELEMS;
        unsigned short* wsWfrag = wsG + GELEMS;
        unsigned short* wsSmall = wsWfrag + WFRAG_ELEMS;
        prep_weights<<<dim3(137), dim3(256), 0, stream>>>(W0, W1, G1, G2, GT, Wc, wsWfrag, wsSmall);
        stageBC_reg<<<dim3(2 * NTILE), dim3(512), 0, stream>>>(x, sf, idx, wsWfrag, wsSmall, wsH, wsG);
        tailDE5<<<dim3(125), dim3(512), 0, stream>>>(wsSmall, wsH, wsG, out);
    } else {
        hyper_fb<<<dim3(NTILE), dim3(512), 0, stream>>>(
            x, sf, idx, W0, W1, G1, G2, GT, Wc, out);
    }
}